// Round 14
// baseline (729.225 us; speedup 1.0000x reference)
//
#include <hip/hip_runtime.h>
#include <cstdint>

namespace {
constexpr int kN = 50000;          // nodes per encoder
constexpr int kE = 200000;         // directed edges per encoder (pre self-loop)
constexpr int kE2 = kE + kN;       // with self loops (per encoder)
constexpr int kG = 256;            // graphs per encoder
constexpr float kNegSlope = 0.2f;
}

using half8   = __attribute__((ext_vector_type(8))) _Float16;
using floatx4 = __attribute__((ext_vector_type(4))) float;

__device__ __forceinline__ void gld_lds16(const void* g, void* l) {
  __builtin_amdgcn_global_load_lds(
      (const __attribute__((address_space(1))) unsigned int*)g,
      (__attribute__((address_space(3))) unsigned int*)l, 16, 0, 0);
}

// fast exp: e^x = 2^(x*log2(e)) via hardware v_exp_f32 (no libm call)
__device__ __forceinline__ float fexp(float x) {
  return __builtin_amdgcn_exp2f(x * 1.44269504088896f);
}

// ---------------- fp16 MFMA GEMM: C[M,N] = A[M,K] @ B[K,N] -----------
// Single-product fp16 (fp32 accumulate). A row-major f16 [M,K]; B
// pre-transposed f16 [N,K]. 128x128 tile, BK=64 (two 32-wide sub-chunks
// per staging barrier: halves barrier count vs BK=32 — R13 showed the
// kernel 70% stalled at MfmaUtil 18% with traffic already minimal).
// 256 threads = 4 waves. NT=4: XCD-aware swizzle (R13: FETCH 202->54 MB).
// __launch_bounds__(256,4): 4 waves/SIMD (R13: VGPR 56).
template <int OUTF16, int NT>
__global__ __launch_bounds__(256, 4) void gemm_f16(
    const _Float16* __restrict__ A, const _Float16* __restrict__ B,
    void* __restrict__ Cv, int M, int N, int K) {
  __shared__ alignas(16) char smem[32768];
  char* sA = smem;            // 16 KB: two 8 KB chunks (k and k+32)
  char* sB = smem + 16384;    // 16 KB
  const int t = threadIdx.x;
  const int w = t >> 6;
  const int l = t & 63;
  int bm, bn;
  if constexpr (NT == 1) {
    bm = blockIdx.x * 128;
    bn = 0;
  } else {  // NT == 4
    const int x = blockIdx.x & 7;
    const int s = blockIdx.x >> 3;
    bm = (((s >> 2) << 3) + x) * 128;
    bn = (s & 3) * 128;
    if (bm >= M) return;  // padded row-tiles (whole block exits: no barrier)
  }
  const int wm = (w & 1) * 64;
  const int wn = (w >> 1) * 64;
  const int quad = l >> 4;
  const int lrow = l & 15;

  floatx4 acc[4][4];
#pragma unroll
  for (int mi = 0; mi < 4; ++mi)
#pragma unroll
    for (int ni = 0; ni < 4; ++ni) acc[mi][ni] = (floatx4){0.f, 0.f, 0.f, 0.f};

  for (int k0 = 0; k0 < K; k0 += 64) {
#pragma unroll
    for (int j = 0; j < 4; ++j) {
      const int s = w * 256 + j * 64 + l;          // slot id 0..1023
      const int ck = s >> 9;                       // 32-wide sub-chunk 0/1
      const int sc = s & 511;
      const int row = ((sc >> 6) << 4) + (sc & 15);  // 0..127
      const int q = (sc >> 4) & 3;
      int ga = bm + row;
      ga = (ga < M) ? ga : (M - 1);                // clamp: keep lanes active
      const int kof = k0 + ck * 32 + q * 8;
      gld_lds16(A + (size_t)ga * K + kof, sA + ck * 8192 + sc * 16);
      gld_lds16(B + (size_t)(bn + row) * K + kof, sB + ck * 8192 + sc * 16);
    }
    __syncthreads();
#pragma unroll
    for (int ck = 0; ck < 2; ++ck) {
      half8 fa[4], fb[4];
#pragma unroll
      for (int mi = 0; mi < 4; ++mi)
        fa[mi] = *(const half8*)(sA + ck * 8192 + ((wm >> 4) + mi) * 1024 + l * 16);
#pragma unroll
      for (int ni = 0; ni < 4; ++ni)
        fb[ni] = *(const half8*)(sB + ck * 8192 + ((wn >> 4) + ni) * 1024 + l * 16);
#pragma unroll
      for (int mi = 0; mi < 4; ++mi)
#pragma unroll
        for (int ni = 0; ni < 4; ++ni)
          acc[mi][ni] = __builtin_amdgcn_mfma_f32_16x16x32_f16(fa[mi], fb[ni],
                                                               acc[mi][ni], 0, 0, 0);
    }
    __syncthreads();
  }
  // epilogue: C/D layout col=lane&15, row=quad*4+reg
  const int colbase = bn + wn + lrow;
#pragma unroll
  for (int mi = 0; mi < 4; ++mi) {
    const int rbase = bm + wm + mi * 16 + quad * 4;
#pragma unroll
    for (int r = 0; r < 4; ++r) {
      const int grow = rbase + r;
      if (grow < M) {
        if constexpr (OUTF16) {
          _Float16* C = (_Float16*)Cv;
#pragma unroll
          for (int ni = 0; ni < 4; ++ni)
            C[(size_t)grow * N + colbase + ni * 16] = (_Float16)acc[mi][ni][r];
        } else {
          float* C = (float*)Cv;
#pragma unroll
          for (int ni = 0; ni < 4; ++ni)
            C[(size_t)grow * N + colbase + ni * 16] = acc[mi][ni][r];
        }
      }
    }
  }
}

// ------- all three weight transposes + f16 casts in one kernel --------
__global__ void wt_split_all(const float* __restrict__ W1, _Float16* Th1,
                             const float* __restrict__ W2, _Float16* Th2,
                             const float* __restrict__ W3, _Float16* Th3) {
  int idx = blockIdx.x * blockDim.x + threadIdx.x;
  const float* W;
  _Float16* Th;
  int K, N;
  if (idx < 64 * 512) {
    W = W1; Th = Th1; K = 64; N = 512;
  } else if (idx < 64 * 512 + 512 * 512) {
    idx -= 64 * 512;
    W = W2; Th = Th2; K = 512; N = 512;
  } else if (idx < 64 * 512 + 512 * 512 + 512 * 128) {
    idx -= 64 * 512 + 512 * 512;
    W = W3; Th = Th3; K = 512; N = 128;
  } else {
    return;
  }
  const int k = idx / N;
  const int n = idx - k * N;
  Th[n * K + k] = (_Float16)W[idx];
}

// ------- combined prep: both x casts + cnt=1 (2N) + total=0 -----------
__global__ void prep2(const float* __restrict__ x0, const float* __restrict__ x1,
                      _Float16* __restrict__ Xh, int* __restrict__ cnt,
                      int* __restrict__ total) {
  const int idx = blockIdx.x * blockDim.x + threadIdx.x;
  const int half = kN * 64;
  if (idx < half) Xh[idx] = (_Float16)x0[idx];
  else if (idx < 2 * half) Xh[idx] = (_Float16)x1[idx - half];
  if (idx < 2 * kN) cnt[idx] = 1;  // the self loop
  if (idx == 0) *total = 0;
}
// ------- single-encoder prep (fallback path) --------------------------
__global__ void prep(const float* __restrict__ X, _Float16* __restrict__ Xh,
                     int* __restrict__ cnt, int* __restrict__ total, int nsplit,
                     int n) {
  const int idx = blockIdx.x * blockDim.x + threadIdx.x;
  if (idx < nsplit) Xh[idx] = (_Float16)X[idx];
  if (idx < n) cnt[idx] = 1;
  if (idx == 0) *total = 0;
}

// ------- per-node attention dots (layers 1-2, f16 h) ------------------
__global__ void node_alpha8(const _Float16* __restrict__ h,
                            const float* __restrict__ a_src,
                            const float* __restrict__ a_dst,
                            float* __restrict__ asrc,
                            float* __restrict__ adst, int n_nodes) {
  const int gtid = blockIdx.x * blockDim.x + threadIdx.x;
  const int node = gtid >> 6;
  const int lane = threadIdx.x & 63;
  if (node >= n_nodes) return;
  const int head = lane >> 4;
  const half8 hv = *(const half8*)(h + (size_t)node * 512 + lane * 8);
  float s1 = 0.f, s2 = 0.f;
#pragma unroll
  for (int j = 0; j < 8; ++j) {
    const float v = (float)hv[j];
    s1 = fmaf(v, a_src[lane * 8 + j], s1);
    s2 = fmaf(v, a_dst[lane * 8 + j], s2);
  }
#pragma unroll
  for (int off = 1; off < 16; off <<= 1) {
    s1 += __shfl_xor(s1, off);
    s2 += __shfl_xor(s2, off);
  }
  if ((lane & 15) == 0) {
    asrc[node * 4 + head] = s1;
    adst[node * 4 + head] = s2;
  }
}

// ------- layer-3 alpha: dots over fp32 h [M,128] (H=1) ----------------
__global__ void node_alpha_l3(const float* __restrict__ h,
                              const float* __restrict__ a_src,
                              const float* __restrict__ a_dst,
                              float* __restrict__ asrc, float* __restrict__ adst,
                              int n_nodes) {
  const int gtid = blockIdx.x * blockDim.x + threadIdx.x;
  const int node = gtid >> 6;
  const int lane = threadIdx.x & 63;
  if (node >= n_nodes) return;
  const float2 v = *(const float2*)(h + (size_t)node * 128 + lane * 2);
  float s1 = fmaf(v.x, a_src[lane * 2], v.y * a_src[lane * 2 + 1]);
  float s2 = fmaf(v.x, a_dst[lane * 2], v.y * a_dst[lane * 2 + 1]);
#pragma unroll
  for (int off = 1; off < 64; off <<= 1) {
    s1 += __shfl_xor(s1, off);
    s2 += __shfl_xor(s2, off);
  }
  if (lane == 0) {
    asrc[node] = s1;
    adst[node] = s2;
  }
}

// ---------------- CSR (by dst) build ----------------------------------
__global__ void count_edges2(const int* __restrict__ d0, const int* __restrict__ d1,
                             int* __restrict__ cnt) {
  const int i = blockIdx.x * blockDim.x + threadIdx.x;
  if (i < kE) atomicAdd(&cnt[d0[i]], 1);
  else if (i < 2 * kE) atomicAdd(&cnt[d1[i - kE] + kN], 1);
}
__global__ void fill_edges2(const int* __restrict__ s0, const int* __restrict__ d0,
                            const int* __restrict__ s1, const int* __restrict__ d1,
                            int* __restrict__ cursor, int* __restrict__ csr) {
  const int i = blockIdx.x * blockDim.x + threadIdx.x;
  if (i < kE) {
    const int p = atomicAdd(&cursor[d0[i]], 1);
    csr[p] = s0[i];
  } else if (i < 2 * kE) {
    const int j = i - kE;
    const int p = atomicAdd(&cursor[d1[j] + kN], 1);
    csr[p] = s1[j] + kN;
  }
}
__global__ void count_edges(const int* __restrict__ dst, int* __restrict__ cnt,
                            int ne) {
  const int i = blockIdx.x * blockDim.x + threadIdx.x;
  if (i < ne) atomicAdd(&cnt[dst[i]], 1);
}
__global__ void fill_edges(const int* __restrict__ src, const int* __restrict__ dst,
                           int* __restrict__ cursor, int* __restrict__ csr, int ne) {
  const int i = blockIdx.x * blockDim.x + threadIdx.x;
  if (i < ne) {
    const int p = atomicAdd(&cursor[dst[i]], 1);
    csr[p] = src[i];
  }
}
__global__ void alloc_ranges(const int* __restrict__ cnt, int* __restrict__ start,
                             int* __restrict__ cursor, int* __restrict__ total,
                             int* __restrict__ csr, int n) {
  const int i = blockIdx.x * blockDim.x + threadIdx.x;
  const int lane = threadIdx.x & 63;
  const int v = (i < n) ? cnt[i] : 0;
  int sc = v;
#pragma unroll
  for (int off = 1; off < 64; off <<= 1) {
    const int t = __shfl_up(sc, off);
    if (lane >= off) sc += t;
  }
  const int wtot = __shfl(sc, 63);
  int base = 0;
  if (lane == 63) base = atomicAdd(total, wtot);
  base = __shfl(base, 63);
  const int st = base + sc - v;
  if (i < n) {
    start[i] = st;
    cursor[i] = st + 1;
    csr[st] = i;  // self loop first
  }
}

// ---------------- GAT aggregate, layers 1-2 (f16 h, fused scores) -----
__global__ void gat_agg4(const _Float16* __restrict__ h,
                         const float* __restrict__ asrc,
                         const float* __restrict__ adst,
                         const int* __restrict__ start, const int* __restrict__ cnt,
                         const int* __restrict__ csr_src,
                         const float* __restrict__ bias,
                         _Float16* __restrict__ outH, int n_nodes) {
  const int gtid = blockIdx.x * blockDim.x + threadIdx.x;
  const int node = gtid >> 6;
  const int lane = threadIdx.x & 63;
  if (node >= n_nodes) return;
  const int ch = lane * 8;
  const int head = lane >> 4;
  const int s = start[node];
  const int c = cnt[node];
  const float ad = adst[node * 4 + head];
  float a0[8], a1[8];
#pragma unroll
  for (int j = 0; j < 8; ++j) { a0[j] = 0.f; a1[j] = 0.f; }
  float d0 = 0.f, d1 = 0.f;
  int i = 0;
  for (; i + 2 <= c; i += 2) {
    const int s0 = csr_src[s + i];
    const int s1 = csr_src[s + i + 1];
    float e0 = asrc[s0 * 4 + head] + ad;
    float e1 = asrc[s1 * 4 + head] + ad;
    e0 = (e0 > 0.f) ? e0 : kNegSlope * e0;
    e1 = (e1 > 0.f) ? e1 : kNegSlope * e1;
    const float w0 = fexp(e0);
    const float w1 = fexp(e1);
    const half8 v0 = *(const half8*)(h + (size_t)s0 * 512 + ch);
    const half8 v1 = *(const half8*)(h + (size_t)s1 * 512 + ch);
    d0 += w0;
    d1 += w1;
#pragma unroll
    for (int j = 0; j < 8; ++j) {
      a0[j] = fmaf(w0, (float)v0[j], a0[j]);
      a1[j] = fmaf(w1, (float)v1[j], a1[j]);
    }
  }
  if (i < c) {
    const int s0 = csr_src[s + i];
    float e0 = asrc[s0 * 4 + head] + ad;
    e0 = (e0 > 0.f) ? e0 : kNegSlope * e0;
    const float w0 = fexp(e0);
    const half8 v0 = *(const half8*)(h + (size_t)s0 * 512 + ch);
    d0 += w0;
#pragma unroll
    for (int j = 0; j < 8; ++j) a0[j] = fmaf(w0, (float)v0[j], a0[j]);
  }
  const float inv = 1.f / (d0 + d1 + 1e-16f);
  half8 H;
#pragma unroll
  for (int j = 0; j < 8; ++j) {
    float v = (a0[j] + a1[j]) * inv + bias[ch + j];
    v = (v > 0.f) ? v : (fexp(v) - 1.f);  // elu via hw exp
    H[j] = (_Float16)v;
  }
  *(half8*)(outH + (size_t)node * 512 + ch) = H;
}

// ---------- GAT aggregate, layer 3 (H=1, fp32, fused scores) ----------
__global__ void gat_agg_l3(const float* __restrict__ h,
                           const float* __restrict__ asrc,
                           const float* __restrict__ adst,
                           const int* __restrict__ start, const int* __restrict__ cnt,
                           const int* __restrict__ csr_src,
                           const float* __restrict__ bias,
                           float* __restrict__ out, int n_nodes) {
  const int gtid = blockIdx.x * blockDim.x + threadIdx.x;
  const int node = gtid >> 6;
  const int lane = threadIdx.x & 63;
  if (node >= n_nodes) return;
  const int s = start[node];
  const int c = cnt[node];
  const float ad = adst[node];
  float2 a0 = make_float2(0.f, 0.f);
  float2 a1 = make_float2(0.f, 0.f);
  float d0 = 0.f, d1 = 0.f;
  int i = 0;
  for (; i + 2 <= c; i += 2) {
    const int s0 = csr_src[s + i];
    const int s1 = csr_src[s + i + 1];
    float e0 = asrc[s0] + ad;
    float e1 = asrc[s1] + ad;
    e0 = (e0 > 0.f) ? e0 : kNegSlope * e0;
    e1 = (e1 > 0.f) ? e1 : kNegSlope * e1;
    const float w0 = fexp(e0);
    const float w1 = fexp(e1);
    const float2 v0 = *(const float2*)(h + (size_t)s0 * 128 + lane * 2);
    const float2 v1 = *(const float2*)(h + (size_t)s1 * 128 + lane * 2);
    d0 += w0;
    d1 += w1;
    a0.x = fmaf(w0, v0.x, a0.x); a1.x = fmaf(w1, v1.x, a1.x);
    a0.y = fmaf(w0, v0.y, a0.y); a1.y = fmaf(w1, v1.y, a1.y);
  }
  if (i < c) {
    const int s0 = csr_src[s + i];
    float e0 = asrc[s0] + ad;
    e0 = (e0 > 0.f) ? e0 : kNegSlope * e0;
    const float w0 = fexp(e0);
    const float2 v0 = *(const float2*)(h + (size_t)s0 * 128 + lane * 2);
    d0 += w0;
    a0.x = fmaf(w0, v0.x, a0.x);
    a0.y = fmaf(w0, v0.y, a0.y);
  }
  const float inv = 1.f / (d0 + d1 + 1e-16f);
  *(float2*)(out + (size_t)node * 128 + lane * 2) =
      make_float2((a0.x + a1.x) * inv + bias[lane * 2],
                  (a0.y + a1.y) * inv + bias[lane * 2 + 1]);
}

// ---------------- global max pool over sorted batch -------------------
__global__ void pool_max(const float* __restrict__ x, const int* __restrict__ batch,
                         float* __restrict__ emb, int n_nodes) {
  __shared__ int lohi[2];
  const int g = blockIdx.x;
  if (threadIdx.x == 0) {
    int lo = 0, hi = n_nodes;
    while (lo < hi) {
      const int mid = (lo + hi) >> 1;
      if (batch[mid] < g) lo = mid + 1; else hi = mid;
    }
    lohi[0] = lo;
    hi = n_nodes;
    while (lo < hi) {
      const int mid = (lo + hi) >> 1;
      if (batch[mid] < g + 1) lo = mid + 1; else hi = mid;
    }
    lohi[1] = lo;
  }
  __syncthreads();
  const int lo = lohi[0], hi = lohi[1];
  const int c = threadIdx.x;  // 128 channels
  float m = -1e30f;
  for (int nid = lo; nid < hi; ++nid) m = fmaxf(m, x[(size_t)nid * 128 + c]);
  emb[g * 128 + c] = (lo < hi) ? m : 0.f;
}

// ---------------- final MLP head --------------------------------------
__global__ void mlp_head(const float* __restrict__ e1, const float* __restrict__ e2,
                         const float* __restrict__ mw1, const float* __restrict__ mb1,
                         const float* __restrict__ mw2, const float* __restrict__ mb2,
                         float* __restrict__ out) {
  __shared__ float z[256];
  __shared__ float red[128];
  const int g = blockIdx.x;
  const int j = threadIdx.x;  // 128
  z[j] = e1[g * 128 + j];
  z[j + 128] = e2[g * 128 + j];
  __syncthreads();
  float acc = mb1[j];
  for (int k = 0; k < 256; ++k) acc = fmaf(z[k], mw1[k * 128 + j], acc);
  acc = fmaxf(acc, 0.f) * mw2[j];
  red[j] = acc;
  __syncthreads();
  for (int s = 64; s > 0; s >>= 1) {
    if (j < s) red[j] += red[j + s];
    __syncthreads();
  }
  if (j == 0) out[g] = red[0] + mb2[0];
}

// ---------------- launcher --------------------------------------------
namespace {
struct Bufs {
  _Float16 *R1h, *R2h;
  float *R1f, *R2f, *asrc, *adst;
  int *cnt, *start, *cursor, *csr, *total;
  _Float16 *Wth1, *Wth2, *Wth3;
  float* emb;
  size_t need;
};

Bufs plan(void* d_ws, int M, int E) {
  Bufs b;
  char* w = (char*)d_ws;
  size_t off = 0;
  auto take = [&](size_t bytes) -> void* {
    void* p = w + off;
    off += (bytes + 255) & ~(size_t)255;
    return p;
  };
  b.R1h = (_Float16*)take((size_t)M * 512 * 2);  // f16 activations
  b.R1f = (float*)b.R1h;                         // layer-3 out alias [M,128]
  b.R2h = (_Float16*)take((size_t)M * 512 * 2);  // h f16; l3 fp32 alias
  b.R2f = (float*)b.R2h;
  b.asrc = (float*)take((size_t)M * 4 * 4);
  b.adst = (float*)take((size_t)M * 4 * 4);
  b.cnt = (int*)take((size_t)M * 4);
  b.start = (int*)take((size_t)M * 4);
  b.cursor = (int*)take((size_t)M * 4);
  b.csr = (int*)take((size_t)E * 4);
  b.total = (int*)take(256);
  b.Wth1 = (_Float16*)take((size_t)64 * 512 * 2);
  b.Wth2 = (_Float16*)take((size_t)512 * 512 * 2);
  b.Wth3 = (_Float16*)take((size_t)512 * 128 * 2);
  b.emb = (float*)take((size_t)2 * kG * 128 * 4);
  b.need = off;
  return b;
}

void run_layers(const Bufs& b, void* const* d_in, int M, hipStream_t stream) {
  const float* as1 = (const float*)d_in[7];
  const float* ad1 = (const float*)d_in[8];
  const float* b1 = (const float*)d_in[9];
  const float* as2 = (const float*)d_in[11];
  const float* ad2 = (const float*)d_in[12];
  const float* b2 = (const float*)d_in[13];
  const float* as3 = (const float*)d_in[15];
  const float* ad3 = (const float*)d_in[16];
  const float* b3 = (const float*)d_in[17];
  const int nodeBlocks = (M * 64) / 256;  // 1 wave/node
  const int MT = (M + 127) / 128;
  const int MTp = (MT + 7) & ~7;          // pad rows to multiple of 8 (XCD map)

  // layer 1: [M,64] @ [64,512], h -> f16 (A1h aliases R1h)
  gemm_f16<1, 4><<<MTp * 4, 256, 0, stream>>>(b.R1h, b.Wth1, b.R2h, M, 512, 64);
  node_alpha8<<<nodeBlocks, 256, 0, stream>>>(b.R2h, as1, ad1, b.asrc, b.adst, M);
  gat_agg4<<<nodeBlocks, 256, 0, stream>>>(b.R2h, b.asrc, b.adst, b.start, b.cnt,
                                           b.csr, b1, b.R1h, M);
  // layer 2: [M,512] @ [512,512], h -> f16
  gemm_f16<1, 4><<<MTp * 4, 256, 0, stream>>>(b.R1h, b.Wth2, b.R2h, M, 512, 512);
  node_alpha8<<<nodeBlocks, 256, 0, stream>>>(b.R2h, as2, ad2, b.asrc, b.adst, M);
  gat_agg4<<<nodeBlocks, 256, 0, stream>>>(b.R2h, b.asrc, b.adst, b.start, b.cnt,
                                           b.csr, b2, b.R1h, M);
  // layer 3: [M,512] @ [512,128], H=1, no elu, fp32 out
  gemm_f16<0, 1><<<MT, 256, 0, stream>>>(b.R1h, b.Wth3, b.R2f, M, 128, 512);
  node_alpha_l3<<<nodeBlocks, 256, 0, stream>>>(b.R2f, as3, ad3, b.asrc, b.adst, M);
  gat_agg_l3<<<nodeBlocks, 256, 0, stream>>>(b.R2f, b.asrc, b.adst, b.start, b.cnt,
                                             b.csr, b3, b.R1f, M);
}
}  // namespace

extern "C" void kernel_launch(void* const* d_in, const int* in_sizes, int n_in,
                              void* d_out, int out_size, void* d_ws, size_t ws_size,
                              hipStream_t stream) {
  (void)in_sizes; (void)n_in; (void)out_size;
  const float* W1 = (const float*)d_in[6];
  const float* W2 = (const float*)d_in[10];
  const float* W3 = (const float*)d_in[14];
  const float* mw1 = (const float*)d_in[18];
  const float* mb1 = (const float*)d_in[19];
  const float* mw2 = (const float*)d_in[20];
  const float* mb2 = (const float*)d_in[21];

  // Prefer combined (both encoders batched, M=2N) if it fits the workspace.
  Bufs bc = plan(d_ws, 2 * kN, 2 * kE2);
  const bool combined = bc.need <= ws_size;
  Bufs b = combined ? bc : plan(d_ws, kN, kE2);

  const int wtot = 64 * 512 + 512 * 512 + 512 * 128;
  wt_split_all<<<(wtot + 255) / 256, 256, 0, stream>>>(W1, b.Wth1, W2, b.Wth2, W3,
                                                       b.Wth3);
  if (combined) {
    const int M = 2 * kN;
    const int* ei0 = (const int*)d_in[1];
    const int* ei1 = (const int*)d_in[4];
    prep2<<<(2 * kN * 64 + 255) / 256, 256, 0, stream>>>(
        (const float*)d_in[0], (const float*)d_in[3], b.R1h, b.cnt, b.total);
    count_edges2<<<(2 * kE + 255) / 256, 256, 0, stream>>>(ei0 + kE, ei1 + kE,
                                                           b.cnt);
    alloc_ranges<<<(M + 255) / 256, 256, 0, stream>>>(b.cnt, b.start, b.cursor,
                                                      b.total, b.csr, M);
    fill_edges2<<<(2 * kE + 255) / 256, 256, 0, stream>>>(ei0, ei0 + kE, ei1,
                                                          ei1 + kE, b.cursor, b.csr);
    run_layers(b, d_in, M, stream);
    for (int enc = 0; enc < 2; ++enc) {
      const int* batch = (const int*)d_in[enc * 3 + 2];
      pool_max<<<kG, 128, 0, stream>>>(b.R1f + (size_t)enc * kN * 128, batch,
                                       b.emb + (size_t)enc * kG * 128, kN);
    }
  } else {
    for (int enc = 0; enc < 2; ++enc) {
      const float* x = (const float*)d_in[enc * 3 + 0];
      const int* ei = (const int*)d_in[enc * 3 + 1];
      const int* batch = (const int*)d_in[enc * 3 + 2];
      prep<<<(kN * 64 + 255) / 256, 256, 0, stream>>>(x, b.R1h, b.cnt, b.total,
                                                      kN * 64, kN);
      count_edges<<<(kE + 255) / 256, 256, 0, stream>>>(ei + kE, b.cnt, kE);
      alloc_ranges<<<(kN + 255) / 256, 256, 0, stream>>>(b.cnt, b.start, b.cursor,
                                                         b.total, b.csr, kN);
      fill_edges<<<(kE + 255) / 256, 256, 0, stream>>>(ei, ei + kE, b.cursor, b.csr,
                                                       kE);
      run_layers(b, d_in, kN, stream);
      pool_max<<<kG, 128, 0, stream>>>(b.R1f, batch, b.emb + (size_t)enc * kG * 128,
                                       kN);
    }
  }
  mlp_head<<<kG, 128, 0, stream>>>(b.emb, b.emb + (size_t)kG * 128, mw1, mb1, mw2,
                                   mb2, (float*)d_out);
}

// Round 15
// 728.307 us; speedup vs baseline: 1.0013x; 1.0013x over previous
//
#include <hip/hip_runtime.h>
#include <cstdint>

namespace {
constexpr int kN = 50000;          // nodes per encoder
constexpr int kE = 200000;         // directed edges per encoder (pre self-loop)
constexpr int kE2 = kE + kN;       // with self loops (per encoder)
constexpr int kG = 256;            // graphs per encoder
constexpr float kNegSlope = 0.2f;
}

using half8   = __attribute__((ext_vector_type(8))) _Float16;
using floatx4 = __attribute__((ext_vector_type(4))) float;

__device__ __forceinline__ void gld_lds16(const void* g, void* l) {
  __builtin_amdgcn_global_load_lds(
      (const __attribute__((address_space(1))) unsigned int*)g,
      (__attribute__((address_space(3))) unsigned int*)l, 16, 0, 0);
}

// fast exp: e^x = 2^(x*log2(e)) via hardware v_exp_f32 (no libm call)
__device__ __forceinline__ float fexp(float x) {
  return __builtin_amdgcn_exp2f(x * 1.44269504088896f);
}

// ---------------- fp16 MFMA GEMM: C[M,N] = A[M,K] @ B[K,N] -----------
// Single-product fp16 (fp32 accumulate). A row-major f16 [M,K]; B
// pre-transposed f16 [N,K]. 128x128 tile, BK=32 (BK=64 was neutral: R14
// — barrier count isn't the binding constraint; this structure's K=512
// plateau is ~444 TF). NT=4: XCD-aware swizzle (R13: FETCH 202->54 MB).
// __launch_bounds__(256,4): 4 waves/SIMD.
template <int OUTF16, int NT>
__global__ __launch_bounds__(256, 4) void gemm_f16(
    const _Float16* __restrict__ A, const _Float16* __restrict__ B,
    void* __restrict__ Cv, int M, int N, int K) {
  __shared__ alignas(16) char smem[16384];
  char* sA = smem;
  char* sB = smem + 8192;
  const int t = threadIdx.x;
  const int w = t >> 6;
  const int l = t & 63;
  int bm, bn;
  if constexpr (NT == 1) {
    bm = blockIdx.x * 128;
    bn = 0;
  } else {  // NT == 4
    const int x = blockIdx.x & 7;
    const int s = blockIdx.x >> 3;
    bm = (((s >> 2) << 3) + x) * 128;
    bn = (s & 3) * 128;
    if (bm >= M) return;  // padded row-tiles (whole block exits: no barrier)
  }
  const int wm = (w & 1) * 64;
  const int wn = (w >> 1) * 64;
  const int quad = l >> 4;
  const int lrow = l & 15;

  floatx4 acc[4][4];
#pragma unroll
  for (int mi = 0; mi < 4; ++mi)
#pragma unroll
    for (int ni = 0; ni < 4; ++ni) acc[mi][ni] = (floatx4){0.f, 0.f, 0.f, 0.f};

  for (int k0 = 0; k0 < K; k0 += 32) {
#pragma unroll
    for (int j = 0; j < 2; ++j) {
      const int s = w * 128 + j * 64 + l;          // slot id 0..511
      const int row = ((s >> 6) << 4) + (s & 15);  // 0..127
      const int q = (s >> 4) & 3;
      int ga = bm + row;
      ga = (ga < M) ? ga : (M - 1);                // clamp: keep lanes active
      gld_lds16(A + (size_t)ga * K + k0 + q * 8, sA + s * 16);
      gld_lds16(B + (size_t)(bn + row) * K + k0 + q * 8, sB + s * 16);
    }
    __syncthreads();
    half8 fa[4], fb[4];
#pragma unroll
    for (int mi = 0; mi < 4; ++mi)
      fa[mi] = *(const half8*)(sA + ((wm >> 4) + mi) * 1024 + l * 16);
#pragma unroll
    for (int ni = 0; ni < 4; ++ni)
      fb[ni] = *(const half8*)(sB + ((wn >> 4) + ni) * 1024 + l * 16);
#pragma unroll
    for (int mi = 0; mi < 4; ++mi)
#pragma unroll
      for (int ni = 0; ni < 4; ++ni)
        acc[mi][ni] = __builtin_amdgcn_mfma_f32_16x16x32_f16(fa[mi], fb[ni],
                                                             acc[mi][ni], 0, 0, 0);
    __syncthreads();
  }
  // epilogue: C/D layout col=lane&15, row=quad*4+reg
  const int colbase = bn + wn + lrow;
#pragma unroll
  for (int mi = 0; mi < 4; ++mi) {
    const int rbase = bm + wm + mi * 16 + quad * 4;
#pragma unroll
    for (int r = 0; r < 4; ++r) {
      const int grow = rbase + r;
      if (grow < M) {
        if constexpr (OUTF16) {
          _Float16* C = (_Float16*)Cv;
#pragma unroll
          for (int ni = 0; ni < 4; ++ni)
            C[(size_t)grow * N + colbase + ni * 16] = (_Float16)acc[mi][ni][r];
        } else {
          float* C = (float*)Cv;
#pragma unroll
          for (int ni = 0; ni < 4; ++ni)
            C[(size_t)grow * N + colbase + ni * 16] = acc[mi][ni][r];
        }
      }
    }
  }
}

// ------- all three weight transposes + f16 casts in one kernel --------
__global__ void wt_split_all(const float* __restrict__ W1, _Float16* Th1,
                             const float* __restrict__ W2, _Float16* Th2,
                             const float* __restrict__ W3, _Float16* Th3) {
  int idx = blockIdx.x * blockDim.x + threadIdx.x;
  const float* W;
  _Float16* Th;
  int K, N;
  if (idx < 64 * 512) {
    W = W1; Th = Th1; K = 64; N = 512;
  } else if (idx < 64 * 512 + 512 * 512) {
    idx -= 64 * 512;
    W = W2; Th = Th2; K = 512; N = 512;
  } else if (idx < 64 * 512 + 512 * 512 + 512 * 128) {
    idx -= 64 * 512 + 512 * 512;
    W = W3; Th = Th3; K = 512; N = 128;
  } else {
    return;
  }
  const int k = idx / N;
  const int n = idx - k * N;
  Th[n * K + k] = (_Float16)W[idx];
}

// ------- combined prep: both x casts + cnt=1 (2N) + total=0 -----------
__global__ void prep2(const float* __restrict__ x0, const float* __restrict__ x1,
                      _Float16* __restrict__ Xh, int* __restrict__ cnt,
                      int* __restrict__ total) {
  const int idx = blockIdx.x * blockDim.x + threadIdx.x;
  const int half = kN * 64;
  if (idx < half) Xh[idx] = (_Float16)x0[idx];
  else if (idx < 2 * half) Xh[idx] = (_Float16)x1[idx - half];
  if (idx < 2 * kN) cnt[idx] = 1;  // the self loop
  if (idx == 0) *total = 0;
}
// ------- single-encoder prep (fallback path) --------------------------
__global__ void prep(const float* __restrict__ X, _Float16* __restrict__ Xh,
                     int* __restrict__ cnt, int* __restrict__ total, int nsplit,
                     int n) {
  const int idx = blockIdx.x * blockDim.x + threadIdx.x;
  if (idx < nsplit) Xh[idx] = (_Float16)X[idx];
  if (idx < n) cnt[idx] = 1;
  if (idx == 0) *total = 0;
}

// ------- per-node attention dots (layers 1-2, f16 h) ------------------
__global__ void node_alpha8(const _Float16* __restrict__ h,
                            const float* __restrict__ a_src,
                            const float* __restrict__ a_dst,
                            float* __restrict__ asrc,
                            float* __restrict__ adst, int n_nodes) {
  const int gtid = blockIdx.x * blockDim.x + threadIdx.x;
  const int node = gtid >> 6;
  const int lane = threadIdx.x & 63;
  if (node >= n_nodes) return;
  const int head = lane >> 4;
  const half8 hv = *(const half8*)(h + (size_t)node * 512 + lane * 8);
  float s1 = 0.f, s2 = 0.f;
#pragma unroll
  for (int j = 0; j < 8; ++j) {
    const float v = (float)hv[j];
    s1 = fmaf(v, a_src[lane * 8 + j], s1);
    s2 = fmaf(v, a_dst[lane * 8 + j], s2);
  }
#pragma unroll
  for (int off = 1; off < 16; off <<= 1) {
    s1 += __shfl_xor(s1, off);
    s2 += __shfl_xor(s2, off);
  }
  if ((lane & 15) == 0) {
    asrc[node * 4 + head] = s1;
    adst[node * 4 + head] = s2;
  }
}

// ------- layer-3 alpha: dots over fp32 h [M,128] (H=1) ----------------
__global__ void node_alpha_l3(const float* __restrict__ h,
                              const float* __restrict__ a_src,
                              const float* __restrict__ a_dst,
                              float* __restrict__ asrc, float* __restrict__ adst,
                              int n_nodes) {
  const int gtid = blockIdx.x * blockDim.x + threadIdx.x;
  const int node = gtid >> 6;
  const int lane = threadIdx.x & 63;
  if (node >= n_nodes) return;
  const float2 v = *(const float2*)(h + (size_t)node * 128 + lane * 2);
  float s1 = fmaf(v.x, a_src[lane * 2], v.y * a_src[lane * 2 + 1]);
  float s2 = fmaf(v.x, a_dst[lane * 2], v.y * a_dst[lane * 2 + 1]);
#pragma unroll
  for (int off = 1; off < 64; off <<= 1) {
    s1 += __shfl_xor(s1, off);
    s2 += __shfl_xor(s2, off);
  }
  if (lane == 0) {
    asrc[node] = s1;
    adst[node] = s2;
  }
}

// ---------------- CSR (by dst) build ----------------------------------
__global__ void count_edges2(const int* __restrict__ d0, const int* __restrict__ d1,
                             int* __restrict__ cnt) {
  const int i = blockIdx.x * blockDim.x + threadIdx.x;
  if (i < kE) atomicAdd(&cnt[d0[i]], 1);
  else if (i < 2 * kE) atomicAdd(&cnt[d1[i - kE] + kN], 1);
}
__global__ void fill_edges2(const int* __restrict__ s0, const int* __restrict__ d0,
                            const int* __restrict__ s1, const int* __restrict__ d1,
                            int* __restrict__ cursor, int* __restrict__ csr) {
  const int i = blockIdx.x * blockDim.x + threadIdx.x;
  if (i < kE) {
    const int p = atomicAdd(&cursor[d0[i]], 1);
    csr[p] = s0[i];
  } else if (i < 2 * kE) {
    const int j = i - kE;
    const int p = atomicAdd(&cursor[d1[j] + kN], 1);
    csr[p] = s1[j] + kN;
  }
}
__global__ void count_edges(const int* __restrict__ dst, int* __restrict__ cnt,
                            int ne) {
  const int i = blockIdx.x * blockDim.x + threadIdx.x;
  if (i < ne) atomicAdd(&cnt[dst[i]], 1);
}
__global__ void fill_edges(const int* __restrict__ src, const int* __restrict__ dst,
                           int* __restrict__ cursor, int* __restrict__ csr, int ne) {
  const int i = blockIdx.x * blockDim.x + threadIdx.x;
  if (i < ne) {
    const int p = atomicAdd(&cursor[dst[i]], 1);
    csr[p] = src[i];
  }
}
__global__ void alloc_ranges(const int* __restrict__ cnt, int* __restrict__ start,
                             int* __restrict__ cursor, int* __restrict__ total,
                             int* __restrict__ csr, int n) {
  const int i = blockIdx.x * blockDim.x + threadIdx.x;
  const int lane = threadIdx.x & 63;
  const int v = (i < n) ? cnt[i] : 0;
  int sc = v;
#pragma unroll
  for (int off = 1; off < 64; off <<= 1) {
    const int t = __shfl_up(sc, off);
    if (lane >= off) sc += t;
  }
  const int wtot = __shfl(sc, 63);
  int base = 0;
  if (lane == 63) base = atomicAdd(total, wtot);
  base = __shfl(base, 63);
  const int st = base + sc - v;
  if (i < n) {
    start[i] = st;
    cursor[i] = st + 1;
    csr[st] = i;  // self loop first
  }
}

// ---------------- GAT aggregate, layers 1-2 (f16 h, fused scores) -----
// 1 wave/node, lane owns 8 ch. 4-wide unrolled main loop: 4 independent
// csr/score/h load chains in flight (deg~5 => most nodes need 1 iter) —
// attacks LLC-latency-bound gathers with 2x outstanding requests.
__global__ void gat_agg4(const _Float16* __restrict__ h,
                         const float* __restrict__ asrc,
                         const float* __restrict__ adst,
                         const int* __restrict__ start, const int* __restrict__ cnt,
                         const int* __restrict__ csr_src,
                         const float* __restrict__ bias,
                         _Float16* __restrict__ outH, int n_nodes) {
  const int gtid = blockIdx.x * blockDim.x + threadIdx.x;
  const int node = gtid >> 6;
  const int lane = threadIdx.x & 63;
  if (node >= n_nodes) return;
  const int ch = lane * 8;
  const int head = lane >> 4;
  const int s = start[node];
  const int c = cnt[node];
  const float ad = adst[node * 4 + head];
  float a0[8], a1[8];
#pragma unroll
  for (int j = 0; j < 8; ++j) { a0[j] = 0.f; a1[j] = 0.f; }
  float d0 = 0.f, d1 = 0.f;
  int i = 0;
  for (; i + 4 <= c; i += 4) {
    const int s0 = csr_src[s + i];
    const int s1 = csr_src[s + i + 1];
    const int s2 = csr_src[s + i + 2];
    const int s3 = csr_src[s + i + 3];
    float e0 = asrc[s0 * 4 + head] + ad;
    float e1 = asrc[s1 * 4 + head] + ad;
    float e2 = asrc[s2 * 4 + head] + ad;
    float e3 = asrc[s3 * 4 + head] + ad;
    e0 = (e0 > 0.f) ? e0 : kNegSlope * e0;
    e1 = (e1 > 0.f) ? e1 : kNegSlope * e1;
    e2 = (e2 > 0.f) ? e2 : kNegSlope * e2;
    e3 = (e3 > 0.f) ? e3 : kNegSlope * e3;
    const float w0 = fexp(e0);
    const float w1 = fexp(e1);
    const float w2 = fexp(e2);
    const float w3 = fexp(e3);
    const half8 v0 = *(const half8*)(h + (size_t)s0 * 512 + ch);
    const half8 v1 = *(const half8*)(h + (size_t)s1 * 512 + ch);
    const half8 v2 = *(const half8*)(h + (size_t)s2 * 512 + ch);
    const half8 v3 = *(const half8*)(h + (size_t)s3 * 512 + ch);
    d0 += w0 + w2;
    d1 += w1 + w3;
#pragma unroll
    for (int j = 0; j < 8; ++j) {
      a0[j] = fmaf(w2, (float)v2[j], fmaf(w0, (float)v0[j], a0[j]));
      a1[j] = fmaf(w3, (float)v3[j], fmaf(w1, (float)v1[j], a1[j]));
    }
  }
  for (; i < c; ++i) {
    const int s0 = csr_src[s + i];
    float e0 = asrc[s0 * 4 + head] + ad;
    e0 = (e0 > 0.f) ? e0 : kNegSlope * e0;
    const float w0 = fexp(e0);
    const half8 v0 = *(const half8*)(h + (size_t)s0 * 512 + ch);
    d0 += w0;
#pragma unroll
    for (int j = 0; j < 8; ++j) a0[j] = fmaf(w0, (float)v0[j], a0[j]);
  }
  const float inv = 1.f / (d0 + d1 + 1e-16f);
  half8 H;
#pragma unroll
  for (int j = 0; j < 8; ++j) {
    float v = (a0[j] + a1[j]) * inv + bias[ch + j];
    v = (v > 0.f) ? v : (fexp(v) - 1.f);  // elu via hw exp
    H[j] = (_Float16)v;
  }
  *(half8*)(outH + (size_t)node * 512 + ch) = H;
}

// ---------- GAT aggregate, layer 3 (H=1, fp32, fused scores) ----------
__global__ void gat_agg_l3(const float* __restrict__ h,
                           const float* __restrict__ asrc,
                           const float* __restrict__ adst,
                           const int* __restrict__ start, const int* __restrict__ cnt,
                           const int* __restrict__ csr_src,
                           const float* __restrict__ bias,
                           float* __restrict__ out, int n_nodes) {
  const int gtid = blockIdx.x * blockDim.x + threadIdx.x;
  const int node = gtid >> 6;
  const int lane = threadIdx.x & 63;
  if (node >= n_nodes) return;
  const int s = start[node];
  const int c = cnt[node];
  const float ad = adst[node];
  float2 a0 = make_float2(0.f, 0.f);
  float2 a1 = make_float2(0.f, 0.f);
  float d0 = 0.f, d1 = 0.f;
  int i = 0;
  for (; i + 4 <= c; i += 4) {
    const int s0 = csr_src[s + i];
    const int s1 = csr_src[s + i + 1];
    const int s2 = csr_src[s + i + 2];
    const int s3 = csr_src[s + i + 3];
    float e0 = asrc[s0] + ad;
    float e1 = asrc[s1] + ad;
    float e2 = asrc[s2] + ad;
    float e3 = asrc[s3] + ad;
    e0 = (e0 > 0.f) ? e0 : kNegSlope * e0;
    e1 = (e1 > 0.f) ? e1 : kNegSlope * e1;
    e2 = (e2 > 0.f) ? e2 : kNegSlope * e2;
    e3 = (e3 > 0.f) ? e3 : kNegSlope * e3;
    const float w0 = fexp(e0);
    const float w1 = fexp(e1);
    const float w2 = fexp(e2);
    const float w3 = fexp(e3);
    const float2 v0 = *(const float2*)(h + (size_t)s0 * 128 + lane * 2);
    const float2 v1 = *(const float2*)(h + (size_t)s1 * 128 + lane * 2);
    const float2 v2 = *(const float2*)(h + (size_t)s2 * 128 + lane * 2);
    const float2 v3 = *(const float2*)(h + (size_t)s3 * 128 + lane * 2);
    d0 += w0 + w2;
    d1 += w1 + w3;
    a0.x = fmaf(w2, v2.x, fmaf(w0, v0.x, a0.x));
    a0.y = fmaf(w2, v2.y, fmaf(w0, v0.y, a0.y));
    a1.x = fmaf(w3, v3.x, fmaf(w1, v1.x, a1.x));
    a1.y = fmaf(w3, v3.y, fmaf(w1, v1.y, a1.y));
  }
  for (; i < c; ++i) {
    const int s0 = csr_src[s + i];
    float e0 = asrc[s0] + ad;
    e0 = (e0 > 0.f) ? e0 : kNegSlope * e0;
    const float w0 = fexp(e0);
    const float2 v0 = *(const float2*)(h + (size_t)s0 * 128 + lane * 2);
    d0 += w0;
    a0.x = fmaf(w0, v0.x, a0.x);
    a0.y = fmaf(w0, v0.y, a0.y);
  }
  const float inv = 1.f / (d0 + d1 + 1e-16f);
  *(float2*)(out + (size_t)node * 128 + lane * 2) =
      make_float2((a0.x + a1.x) * inv + bias[lane * 2],
                  (a0.y + a1.y) * inv + bias[lane * 2 + 1]);
}

// ---------------- global max pool over sorted batch -------------------
__global__ void pool_max(const float* __restrict__ x, const int* __restrict__ batch,
                         float* __restrict__ emb, int n_nodes) {
  __shared__ int lohi[2];
  const int g = blockIdx.x;
  if (threadIdx.x == 0) {
    int lo = 0, hi = n_nodes;
    while (lo < hi) {
      const int mid = (lo + hi) >> 1;
      if (batch[mid] < g) lo = mid + 1; else hi = mid;
    }
    lohi[0] = lo;
    hi = n_nodes;
    while (lo < hi) {
      const int mid = (lo + hi) >> 1;
      if (batch[mid] < g + 1) lo = mid + 1; else hi = mid;
    }
    lohi[1] = lo;
  }
  __syncthreads();
  const int lo = lohi[0], hi = lohi[1];
  const int c = threadIdx.x;  // 128 channels
  float m = -1e30f;
  for (int nid = lo; nid < hi; ++nid) m = fmaxf(m, x[(size_t)nid * 128 + c]);
  emb[g * 128 + c] = (lo < hi) ? m : 0.f;
}

// ---------------- final MLP head --------------------------------------
__global__ void mlp_head(const float* __restrict__ e1, const float* __restrict__ e2,
                         const float* __restrict__ mw1, const float* __restrict__ mb1,
                         const float* __restrict__ mw2, const float* __restrict__ mb2,
                         float* __restrict__ out) {
  __shared__ float z[256];
  __shared__ float red[128];
  const int g = blockIdx.x;
  const int j = threadIdx.x;  // 128
  z[j] = e1[g * 128 + j];
  z[j + 128] = e2[g * 128 + j];
  __syncthreads();
  float acc = mb1[j];
  for (int k = 0; k < 256; ++k) acc = fmaf(z[k], mw1[k * 128 + j], acc);
  acc = fmaxf(acc, 0.f) * mw2[j];
  red[j] = acc;
  __syncthreads();
  for (int s = 64; s > 0; s >>= 1) {
    if (j < s) red[j] += red[j + s];
    __syncthreads();
  }
  if (j == 0) out[g] = red[0] + mb2[0];
}

// ---------------- launcher --------------------------------------------
namespace {
struct Bufs {
  _Float16 *R1h, *R2h;
  float *R1f, *R2f, *asrc, *adst;
  int *cnt, *start, *cursor, *csr, *total;
  _Float16 *Wth1, *Wth2, *Wth3;
  float* emb;
  size_t need;
};

Bufs plan(void* d_ws, int M, int E) {
  Bufs b;
  char* w = (char*)d_ws;
  size_t off = 0;
  auto take = [&](size_t bytes) -> void* {
    void* p = w + off;
    off += (bytes + 255) & ~(size_t)255;
    return p;
  };
  b.R1h = (_Float16*)take((size_t)M * 512 * 2);  // f16 activations
  b.R1f = (float*)b.R1h;                         // layer-3 out alias [M,128]
  b.R2h = (_Float16*)take((size_t)M * 512 * 2);  // h f16; l3 fp32 alias
  b.R2f = (float*)b.R2h;
  b.asrc = (float*)take((size_t)M * 4 * 4);
  b.adst = (float*)take((size_t)M * 4 * 4);
  b.cnt = (int*)take((size_t)M * 4);
  b.start = (int*)take((size_t)M * 4);
  b.cursor = (int*)take((size_t)M * 4);
  b.csr = (int*)take((size_t)E * 4);
  b.total = (int*)take(256);
  b.Wth1 = (_Float16*)take((size_t)64 * 512 * 2);
  b.Wth2 = (_Float16*)take((size_t)512 * 512 * 2);
  b.Wth3 = (_Float16*)take((size_t)512 * 128 * 2);
  b.emb = (float*)take((size_t)2 * kG * 128 * 4);
  b.need = off;
  return b;
}

void run_layers(const Bufs& b, void* const* d_in, int M, hipStream_t stream) {
  const float* as1 = (const float*)d_in[7];
  const float* ad1 = (const float*)d_in[8];
  const float* b1 = (const float*)d_in[9];
  const float* as2 = (const float*)d_in[11];
  const float* ad2 = (const float*)d_in[12];
  const float* b2 = (const float*)d_in[13];
  const float* as3 = (const float*)d_in[15];
  const float* ad3 = (const float*)d_in[16];
  const float* b3 = (const float*)d_in[17];
  const int nodeBlocks = (M * 64) / 256;  // 1 wave/node
  const int MT = (M + 127) / 128;
  const int MTp = (MT + 7) & ~7;          // pad rows to multiple of 8 (XCD map)

  // layer 1: [M,64] @ [64,512], h -> f16 (A1h aliases R1h)
  gemm_f16<1, 4><<<MTp * 4, 256, 0, stream>>>(b.R1h, b.Wth1, b.R2h, M, 512, 64);
  node_alpha8<<<nodeBlocks, 256, 0, stream>>>(b.R2h, as1, ad1, b.asrc, b.adst, M);
  gat_agg4<<<nodeBlocks, 256, 0, stream>>>(b.R2h, b.asrc, b.adst, b.start, b.cnt,
                                           b.csr, b1, b.R1h, M);
  // layer 2: [M,512] @ [512,512], h -> f16
  gemm_f16<1, 4><<<MTp * 4, 256, 0, stream>>>(b.R1h, b.Wth2, b.R2h, M, 512, 512);
  node_alpha8<<<nodeBlocks, 256, 0, stream>>>(b.R2h, as2, ad2, b.asrc, b.adst, M);
  gat_agg4<<<nodeBlocks, 256, 0, stream>>>(b.R2h, b.asrc, b.adst, b.start, b.cnt,
                                           b.csr, b2, b.R1h, M);
  // layer 3: [M,512] @ [512,128], H=1, no elu, fp32 out
  gemm_f16<0, 1><<<MT, 256, 0, stream>>>(b.R1h, b.Wth3, b.R2f, M, 128, 512);
  node_alpha_l3<<<nodeBlocks, 256, 0, stream>>>(b.R2f, as3, ad3, b.asrc, b.adst, M);
  gat_agg_l3<<<nodeBlocks, 256, 0, stream>>>(b.R2f, b.asrc, b.adst, b.start, b.cnt,
                                             b.csr, b3, b.R1f, M);
}
}  // namespace

extern "C" void kernel_launch(void* const* d_in, const int* in_sizes, int n_in,
                              void* d_out, int out_size, void* d_ws, size_t ws_size,
                              hipStream_t stream) {
  (void)in_sizes; (void)n_in; (void)out_size;
  const float* W1 = (const float*)d_in[6];
  const float* W2 = (const float*)d_in[10];
  const float* W3 = (const float*)d_in[14];
  const float* mw1 = (const float*)d_in[18];
  const float* mb1 = (const float*)d_in[19];
  const float* mw2 = (const float*)d_in[20];
  const float* mb2 = (const float*)d_in[21];

  // Prefer combined (both encoders batched, M=2N) if it fits the workspace.
  Bufs bc = plan(d_ws, 2 * kN, 2 * kE2);
  const bool combined = bc.need <= ws_size;
  Bufs b = combined ? bc : plan(d_ws, kN, kE2);

  const int wtot = 64 * 512 + 512 * 512 + 512 * 128;
  wt_split_all<<<(wtot + 255) / 256, 256, 0, stream>>>(W1, b.Wth1, W2, b.Wth2, W3,
                                                       b.Wth3);
  if (combined) {
    const int M = 2 * kN;
    const int* ei0 = (const int*)d_in[1];
    const int* ei1 = (const int*)d_in[4];
    prep2<<<(2 * kN * 64 + 255) / 256, 256, 0, stream>>>(
        (const float*)d_in[0], (const float*)d_in[3], b.R1h, b.cnt, b.total);
    count_edges2<<<(2 * kE + 255) / 256, 256, 0, stream>>>(ei0 + kE, ei1 + kE,
                                                           b.cnt);
    alloc_ranges<<<(M + 255) / 256, 256, 0, stream>>>(b.cnt, b.start, b.cursor,
                                                      b.total, b.csr, M);
    fill_edges2<<<(2 * kE + 255) / 256, 256, 0, stream>>>(ei0, ei0 + kE, ei1,
                                                          ei1 + kE, b.cursor, b.csr);
    run_layers(b, d_in, M, stream);
    for (int enc = 0; enc < 2; ++enc) {
      const int* batch = (const int*)d_in[enc * 3 + 2];
      pool_max<<<kG, 128, 0, stream>>>(b.R1f + (size_t)enc * kN * 128, batch,
                                       b.emb + (size_t)enc * kG * 128, kN);
    }
  } else {
    for (int enc = 0; enc < 2; ++enc) {
      const float* x = (const float*)d_in[enc * 3 + 0];
      const int* ei = (const int*)d_in[enc * 3 + 1];
      const int* batch = (const int*)d_in[enc * 3 + 2];
      prep<<<(kN * 64 + 255) / 256, 256, 0, stream>>>(x, b.R1h, b.cnt, b.total,
                                                      kN * 64, kN);
      count_edges<<<(kE + 255) / 256, 256, 0, stream>>>(ei + kE, b.cnt, kE);
      alloc_ranges<<<(kN + 255) / 256, 256, 0, stream>>>(b.cnt, b.start, b.cursor,
                                                         b.total, b.csr, kN);
      fill_edges<<<(kE + 255) / 256, 256, 0, stream>>>(ei, ei + kE, b.cursor, b.csr,
                                                       kE);
      run_layers(b, d_in, kN, stream);
      pool_max<<<kG, 128, 0, stream>>>(b.R1f, batch, b.emb + (size_t)enc * kG * 128,
                                       kN);
    }
  }
  mlp_head<<<kG, 128, 0, stream>>>(b.emb, b.emb + (size_t)kG * 128, mw1, mb1, mw2,
                                   mb2, (float*)d_out);
}